// Round 7
// baseline (1191.992 us; speedup 1.0000x reference)
//
#include <hip/hip_runtime.h>

typedef _Float16 f16;
typedef f16  half8 __attribute__((ext_vector_type(8)));
typedef float f32x4 __attribute__((ext_vector_type(4)));

#define B_   32
#define C_   1024
#define HW_  784
#define BQ   64

// Fragment-packed workspace layouts (offsets in f16 elements):
//  mA   [b][panel=c>>4][kc=0..23][lane]  half8 along k=kc*32+(lane>>4)*8, row c=panel*16+(lane&15)
//  tailA[b][panel][sl=0..1][l15]         half8 along k=768+sl*8 (valid lanes l4<2)
//  mV   [b][pd=d>>4][kt=kv>>5][lane]     half8 along kv=kt*32+(lane>>4)*8, row d=pd*16+(lane&15)
#define MA_BATCH  786432ull        // 64*24*512
#define TA_OFF    25165824ull      // 32*MA_BATCH
#define TA_BATCH  16384ull         // 64*2*16*8
#define MV_OFF    25690112ull      // TA_OFF + 32*TA_BATCH
#define MV_BATCH  802816ull        // 49*32*512
// total = (MV_OFF + 32*MV_BATCH)*2 = 102,760,448 bytes

// ---------------------------------------------------------------------------
// Prep: build mA / tailA / mV from x (f32 -> f16, fragment-packed).
// ---------------------------------------------------------------------------
__global__ __launch_bounds__(256)
void prep_kernel(const float* __restrict__ x, f16* __restrict__ ws) {
  __shared__ f16 lt[64][72];   // padded transpose tile
  const int bi = blockIdx.x;               // b*208 + ct*13 + ht
  const int ht = bi % 13;
  const int ct = (bi / 13) & 15;
  const int b  = bi / 208;
  const int h0 = ht * 64, c0 = ct * 64;
  const int t = threadIdx.x, r = t >> 2, q = t & 3;

  f16* mA = ws + (size_t)b * MA_BATCH;
  f16* tA = ws + TA_OFF + (size_t)b * TA_BATCH;
  f16* mV = ws + MV_OFF + (size_t)b * MV_BATCH;

  const int c  = c0 + r;
  const int pc = c >> 4, cl = c & 15;
  const int hq = h0 + q * 16;
  if (hq < HW_) {
    const float* src = x + (size_t)b * (C_ * HW_) + (size_t)c * HW_ + hq;
    float f[16];
#pragma unroll
    for (int j = 0; j < 4; ++j) ((float4*)f)[j] = ((const float4*)src)[j];
    f16 h[16];
#pragma unroll
    for (int j = 0; j < 16; ++j) h[j] = (f16)f[j];
    if (hq < 768) {
      const int kc = hq >> 5;
      const int l4 = (hq >> 3) & 3;          // 0 or 2
      f16* d0 = mA + ((size_t)pc * 24 + kc) * 512 + ((l4    ) * 16 + cl) * 8;
      f16* d1 = mA + ((size_t)pc * 24 + kc) * 512 + ((l4 + 1) * 16 + cl) * 8;
      *(half8*)d0 = *(half8*)h;
      *(half8*)d1 = *(half8*)(h + 8);
    } else {                                  // hq == 768: tail chunk
      f16* d0 = tA + pc * 256 + cl * 8;
      f16* d1 = tA + pc * 256 + 128 + cl * 8;
      *(half8*)d0 = *(half8*)h;
      *(half8*)d1 = *(half8*)(h + 8);
    }
    *(half8*)&lt[r][q * 16]     = *(half8*)h;
    *(half8*)&lt[r][q * 16 + 8] = *(half8*)(h + 8);
  }
  __syncthreads();
  // transposed side -> mV (d = hw, kv = c)
  if (h0 + r < HW_) {
    f16 g[16];
#pragma unroll
    for (int j = 0; j < 16; ++j) g[j] = lt[q * 16 + j][r];
    const int d  = h0 + r;
    const int pd = d >> 4, dl = d & 15;
    const int kv = c0 + q * 16;
    const int kt = kv >> 5;
    const int l4 = (kv >> 3) & 3;            // 0 or 2
    f16* e0 = mV + ((size_t)pd * 32 + kt) * 512 + ((l4    ) * 16 + dl) * 8;
    f16* e1 = mV + ((size_t)pd * 32 + kt) * 512 + ((l4 + 1) * 16 + dl) * 8;
    *(half8*)e0 = *(half8*)g;
    *(half8*)e1 = *(half8*)(g + 8);
  }
}

// ---------------------------------------------------------------------------
// Main: r6 structure + 1-deep register prefetch in both GEMM phases.
// ---------------------------------------------------------------------------
__global__ __launch_bounds__(1024, 4)
void chanattn_main(const float* __restrict__ x, const f16* __restrict__ ws,
                   float* __restrict__ out) {
  __shared__ f16 Pl[BQ * C_];   // 128 KiB
  char* Pb = (char*)Pl;

  const int bi   = blockIdx.x;
  const int slot = bi >> 3;
  const int b    = ((slot >> 4) << 3) | (bi & 7);   // same-batch WGs share an XCD
  const int rb   = slot & 15;
  const int q0   = rb * BQ;

  const int tid  = threadIdx.x;
  const int w    = tid >> 6;    // 0..15
  const int lane = tid & 63;
  const int l15  = lane & 15;
  const int l4   = lane >> 4;

  const f16* mA = ws + (size_t)b * MA_BATCH;
  const f16* tA = ws + TA_OFF + (size_t)b * TA_BATCH;
  const f16* mV = ws + MV_OFF + (size_t)b * MV_BATCH;

  const int pa = q0 >> 4;       // A panel base (rb*4)

  // per-fragment base pointers (lane folded in); chunk kc = +kc*512
  const f16* aB[4]; const f16* bB[4];
#pragma unroll
  for (int rf = 0; rf < 4; ++rf) aB[rf] = mA + (size_t)(pa + rf) * 24 * 512 + lane * 8;
#pragma unroll
  for (int cf = 0; cf < 4; ++cf) bB[cf] = mA + (size_t)(w * 4 + cf) * 24 * 512 + lane * 8;

#define LDK(kc, A, Bv) do {                                                    \
  _Pragma("unroll") for (int rf_ = 0; rf_ < 4; ++rf_)                          \
    A[rf_] = *(const half8*)(aB[rf_] + (size_t)(kc) * 512);                    \
  _Pragma("unroll") for (int cf_ = 0; cf_ < 4; ++cf_)                          \
    Bv[cf_] = *(const half8*)(bB[cf_] + (size_t)(kc) * 512);                   \
} while (0)

#define LDTAIL(A, Bv) do {                                                     \
  _Pragma("unroll") for (int rf_ = 0; rf_ < 4; ++rf_) {                        \
    half8 v_ = {};                                                             \
    if (l4 < 2) v_ = *(const half8*)(tA + (pa + rf_) * 256 + lane * 8);        \
    A[rf_] = v_; }                                                             \
  _Pragma("unroll") for (int cf_ = 0; cf_ < 4; ++cf_) {                        \
    half8 v_ = {};                                                             \
    if (l4 < 2) v_ = *(const half8*)(tA + (w * 4 + cf_) * 256 + lane * 8);     \
    Bv[cf_] = v_; }                                                            \
} while (0)

#define MFMA16(A, Bv) do {                                                     \
  _Pragma("unroll") for (int rf_ = 0; rf_ < 4; ++rf_)                          \
    _Pragma("unroll") for (int cf_ = 0; cf_ < 4; ++cf_)                        \
      acc[rf_][cf_] = __builtin_amdgcn_mfma_f32_16x16x32_f16(A[rf_], Bv[cf_],  \
                                                acc[rf_][cf_], 0, 0, 0);       \
} while (0)

  // ---------------- Phase 1: raw scores, prefetched ----------------
  {
    f32x4 acc[4][4] = {};
    half8 A0[4], B0[4], A1[4], B1[4];
    LDK(0, A0, B0);
    for (int kc = 0; kc < 24; kc += 2) {
      LDK(kc + 1, A1, B1);
      MFMA16(A0, B0);
      if (kc + 2 < 24) { LDK(kc + 2, A0, B0); } else { LDTAIL(A0, B0); }
      MFMA16(A1, B1);
    }
    MFMA16(A0, B0);   // tail chunk (zero-padded lanes)

    // write raw scores -> P (XOR swizzle)
#pragma unroll
    for (int rf = 0; rf < 4; ++rf)
#pragma unroll
      for (int cf = 0; cf < 4; ++cf)
#pragma unroll
        for (int r = 0; r < 4; ++r) {
          const int row = rf * 16 + l4 * 4 + r;     // C/D: col=lane&15, row=(lane>>4)*4+reg
          const int col = w * 64 + cf * 16 + l15;
          int byte = row * 2048 + col * 2;
          byte ^= (row & 7) << 4;
          *(f16*)(Pb + byte) = (f16)acc[rf][cf][r];
        }
  }
  __syncthreads();

  // ---------------- softmax, rows w*4..w*4+3 (lane-consecutive 16B) ----------------
  {
    const float ksc = 0.045084223f;   // log2(e)/32
    for (int rr = 0; rr < 4; ++rr) {
      const int row = w * 4 + rr;
      const int sw  = (row & 7) << 4;
      char* rbase = Pb + row * 2048;
      const int p0 = (lane * 16) ^ sw;
      half8 v0 = *(half8*)(rbase + p0);
      half8 v1 = *(half8*)(rbase + 1024 + p0);
      float f[16];
#pragma unroll
      for (int e = 0; e < 8; ++e) { f[e] = (float)v0[e]; f[e+8] = (float)v1[e]; }
      float mx = f[0];
#pragma unroll
      for (int e = 1; e < 16; ++e) mx = fmaxf(mx, f[e]);
      for (int d = 1; d < 64; d <<= 1) mx = fmaxf(mx, __shfl_xor(mx, d));
      float sum = 0.f;
#pragma unroll
      for (int e = 0; e < 16; ++e) { f[e] = exp2f((f[e] - mx) * ksc); sum += f[e]; }
      for (int d = 1; d < 64; d <<= 1) sum += __shfl_xor(sum, d);
      const float inv = 1.f / sum;
#pragma unroll
      for (int e = 0; e < 8; ++e) { v0[e] = (f16)(f[e]*inv); v1[e] = (f16)(f[e+8]*inv); }
      *(half8*)(rbase + p0) = v0;
      *(half8*)(rbase + 1024 + p0) = v1;
    }
  }
  __syncthreads();

  // ---------------- Phase 2: y = P . V ; si outer, t inner, prefetched ----------------
#define LDP(t, af) do {                                                        \
  _Pragma("unroll") for (int rf_ = 0; rf_ < 4; ++rf_)                          \
    _Pragma("unroll") for (int kf_ = 0; kf_ < 2; ++kf_) {                      \
      const int row_ = rf_ * 16 + l15;                                         \
      int byte_ = row_ * 2048 + (t) * 128 + kf_ * 64 + (l4 << 4);              \
      byte_ ^= (row_ & 7) << 4;                                                \
      af[rf_ * 2 + kf_] = *(const half8*)(Pb + byte_); }                       \
} while (0)

#define LDV(t, vv) do {                                                        \
  vv[0] = *(const half8*)(vb + (size_t)((t) * 2    ) * 512 + lane * 8);        \
  vv[1] = *(const half8*)(vb + (size_t)((t) * 2 + 1) * 512 + lane * 8);        \
} while (0)

#define MM8(af, vv) do {                                                       \
  _Pragma("unroll") for (int kf_ = 0; kf_ < 2; ++kf_)                          \
    _Pragma("unroll") for (int rf_ = 0; rf_ < 4; ++rf_)                        \
      a2[rf_] = __builtin_amdgcn_mfma_f32_16x16x32_f16(af[rf_ * 2 + kf_],      \
                                            vv[kf_], a2[rf_], 0, 0, 0);        \
} while (0)

  {
    const int nsi = (w == 0) ? 4 : 3;          // s = w+16*si < 49
    for (int si = 0; si < nsi; ++si) {
      const int s = w + 16 * si;
      const f16* vb = mV + (size_t)s * 32 * 512;
      f32x4 a2[4] = {};
      half8 af0[8], af1[8], v0[2], v1[2];
      LDP(0, af0); LDV(0, v0);
      for (int t = 0; t < 16; t += 2) {
        LDP(t + 1, af1); LDV(t + 1, v1);
        MM8(af0, v0);
        if (t + 2 < 16) { LDP(t + 2, af0); LDV(t + 2, v0); }
        MM8(af1, v1);
      }
      // epilogue for this d-strip
      const int d = s * 16 + l15;
#pragma unroll
      for (int rf = 0; rf < 4; ++rf)
#pragma unroll
        for (int r = 0; r < 4; ++r) {
          const size_t idx = (size_t)(b * C_ + q0 + rf * 16 + l4 * 4 + r) * HW_ + d;
          out[idx] = x[idx] + a2[rf][r];
        }
    }
  }
}

// ---------------------------------------------------------------------------
// Fallback (round-1 kernel): only if ws too small.
// ---------------------------------------------------------------------------
__device__ __forceinline__ half8 pack8(const float4& a, const float4& b) {
  half8 r;
  r[0]=(f16)a.x; r[1]=(f16)a.y; r[2]=(f16)a.z; r[3]=(f16)a.w;
  r[4]=(f16)b.x; r[5]=(f16)b.y; r[6]=(f16)b.z; r[7]=(f16)b.w;
  return r;
}

__global__ __launch_bounds__(512, 2)
void chanattn_fallback(const float* __restrict__ x, float* __restrict__ out) {
  __shared__ f16 Pl[BQ * C_];
  const int bi   = blockIdx.x;
  const int slot = bi >> 3;
  const int b    = ((slot >> 4) << 3) | (bi & 7);
  const int rb   = slot & 15;
  const int q0   = rb * BQ;
  const int tid  = threadIdx.x;
  const int w    = tid >> 6;
  const int lane = tid & 63;
  const int l15  = lane & 15;
  const int l4   = lane >> 4;
  const float* mb = x + (size_t)b * (C_ * HW_);
  char* Pb = (char*)Pl;
  {
    const int cw = w * 128;
    for (int tile = 0; tile < 2; ++tile) {
      const int c0 = cw + tile * 64;
      f32x4 acc[4][4] = {};
      for (int kc = 0; kc < 25; ++kc) {
        const int k0 = kc * 32 + l4 * 8;
        const bool ok = (k0 < HW_);
        half8 afr[4], bfr[4];
#pragma unroll
        for (int rf = 0; rf < 4; ++rf) {
          if (ok) { const float4* p = (const float4*)(mb + (q0 + rf*16 + l15) * HW_ + k0); afr[rf] = pack8(p[0], p[1]); }
          else {
#pragma unroll
            for (int e = 0; e < 8; ++e) afr[rf][e] = (f16)0.f; }
        }
#pragma unroll
        for (int cf = 0; cf < 4; ++cf) {
          if (ok) { const float4* p = (const float4*)(mb + (c0 + cf*16 + l15) * HW_ + k0); bfr[cf] = pack8(p[0], p[1]); }
          else {
#pragma unroll
            for (int e = 0; e < 8; ++e) bfr[cf][e] = (f16)0.f; }
        }
#pragma unroll
        for (int rf = 0; rf < 4; ++rf)
#pragma unroll
          for (int cf = 0; cf < 4; ++cf)
            acc[rf][cf] = __builtin_amdgcn_mfma_f32_16x16x32_f16(afr[rf], bfr[cf], acc[rf][cf], 0, 0, 0);
      }
#pragma unroll
      for (int rf = 0; rf < 4; ++rf)
#pragma unroll
        for (int cf = 0; cf < 4; ++cf)
#pragma unroll
          for (int r = 0; r < 4; ++r) {
            const int row = rf*16 + l4*4 + r;
            const int col = c0 + cf*16 + l15;
            int byte = row*2048 + col*2;
            byte ^= (row & 7) << 4;
            *(f16*)(Pb + byte) = (f16)acc[rf][cf][r];
          }
    }
  }
  __syncthreads();
  {
    const float ksc = 0.045084223f;
    for (int rr = 0; rr < 8; ++rr) {
      const int row = w*8 + rr;
      const int sw  = (row & 7) << 4;
      char* rbase = Pb + row*2048;
      const int p0 = (lane * 16) ^ sw;
      half8 v0 = *(half8*)(rbase + p0);
      half8 v1 = *(half8*)(rbase + 1024 + p0);
      float f[16];
#pragma unroll
      for (int e = 0; e < 8; ++e) { f[e] = (float)v0[e]; f[e+8] = (float)v1[e]; }
      float mx = f[0];
#pragma unroll
      for (int e = 1; e < 16; ++e) mx = fmaxf(mx, f[e]);
      for (int d = 1; d < 64; d <<= 1) mx = fmaxf(mx, __shfl_xor(mx, d));
      float sum = 0.f;
#pragma unroll
      for (int e = 0; e < 16; ++e) { f[e] = exp2f((f[e] - mx) * ksc); sum += f[e]; }
      for (int d = 1; d < 64; d <<= 1) sum += __shfl_xor(sum, d);
      const float inv = 1.f / sum;
#pragma unroll
      for (int e = 0; e < 8; ++e) { v0[e] = (f16)(f[e]*inv); v1[e] = (f16)(f[e+8]*inv); }
      *(half8*)(rbase + p0) = v0;
      *(half8*)(rbase + 1024 + p0) = v1;
    }
  }
  __syncthreads();
  {
    f32x4 acc[7][4] = {};
    for (int t = 0; t < 16; ++t) {
      half8 afr[4][2];
#pragma unroll
      for (int rf = 0; rf < 4; ++rf)
#pragma unroll
        for (int kf = 0; kf < 2; ++kf) {
          const int row = rf*16 + l15;
          int byte = row*2048 + t*128 + kf*64 + l4*16;
          byte ^= (row & 7) << 4;
          afr[rf][kf] = *(half8*)(Pb + byte);
        }
#pragma unroll
      for (int si = 0; si < 7; ++si) {
        const int s = w + 8*si;
        if (s < 49) {
          const int d = s*16 + l15;
#pragma unroll
          for (int kf = 0; kf < 2; ++kf) {
            const int kv = t*64 + kf*32 + l4*8;
            half8 bfr;
#pragma unroll
            for (int e = 0; e < 8; ++e) bfr[e] = (f16)mb[(kv + e) * HW_ + d];
#pragma unroll
            for (int rf = 0; rf < 4; ++rf)
              acc[si][rf] = __builtin_amdgcn_mfma_f32_16x16x32_f16(afr[rf][kf], bfr, acc[si][rf], 0, 0, 0);
          }
        }
      }
    }
#pragma unroll
    for (int si = 0; si < 7; ++si) {
      const int s = w + 8*si;
      if (s < 49) {
        const int d = s*16 + l15;
#pragma unroll
        for (int rf = 0; rf < 4; ++rf)
#pragma unroll
          for (int r = 0; r < 4; ++r) {
            const size_t idx = (size_t)(b*C_ + q0 + rf*16 + l4*4 + r) * HW_ + d;
            out[idx] = x[idx] + acc[si][rf][r];
          }
      }
    }
  }
}

extern "C" void kernel_launch(void* const* d_in, const int* in_sizes, int n_in,
                              void* d_out, int out_size, void* d_ws, size_t ws_size,
                              hipStream_t stream) {
  const float* x = (const float*)d_in[0];
  float* out = (float*)d_out;
  const size_t need = (MV_OFF + 32ull * MV_BATCH) * 2;   // 102,760,448 B
  if (ws_size >= need) {
    f16* ws = (f16*)d_ws;
    prep_kernel<<<dim3(32 * 16 * 13), dim3(256), 0, stream>>>(x, ws);
    chanattn_main<<<dim3(512), dim3(1024), 0, stream>>>(x, ws, out);
  } else {
    chanattn_fallback<<<dim3(512), dim3(512), 0, stream>>>(x, out);
  }
}

// Round 8
// 611.520 us; speedup vs baseline: 1.9492x; 1.9492x over previous
//
#include <hip/hip_runtime.h>

typedef _Float16 f16;
typedef f16  half8  __attribute__((ext_vector_type(8)));
typedef float f32x4  __attribute__((ext_vector_type(4)));
typedef float f32x16 __attribute__((ext_vector_type(16)));

#define B_   32
#define C_   1024
#define HW_  784
#define BQ   64

// Fragment-packed ws layouts for 32x32x16 MFMA (f16 elems):
//  mA32 [b][p=c>>5][kt=hw>>4 (49)][lane*8] : row=lane&31 -> c=p*32+row, k=kt*16+(lane>>5)*8+e
//  mV32 [b][pd=d>>5 (24)][kt=kv>>4 (64)][lane*8] : col=lane&31 -> d, k=kv
//  tl   [b][kt (64)][256] : compact d=768..783 panel; valid lanes (lane&31)<16,
//        offset = kt*256 + (lane>>5)*128 + (lane&15)*8
#define MA_BATCH  802816ull      // 32*49*512
#define MV_OFF    25690112ull    // 32*MA_BATCH
#define MV_BATCH  786432ull      // 24*64*512
#define TL_OFF    50855936ull    // MV_OFF + 32*MV_BATCH
#define TL_BATCH  16384ull       // 64*256
// total = (TL_OFF + 32*TL_BATCH)*2 = 102,760,448 bytes (exact ws fit)

// ---------------------------------------------------------------------------
// Prep: fragment-pack x into mA32 / mV32 / tl (f32 -> f16).
// ---------------------------------------------------------------------------
__global__ __launch_bounds__(256)
void prep_kernel(const float* __restrict__ x, f16* __restrict__ ws) {
  __shared__ f16 lt[64][72];
  const int bi = blockIdx.x;               // b*208 + ct*13 + ht
  const int ht = bi % 13;
  const int ct = (bi / 13) & 15;
  const int b  = bi / 208;
  const int h0 = ht * 64, c0 = ct * 64;
  const int t = threadIdx.x, r = t >> 2, q = t & 3;

  f16* mA = ws + (size_t)b * MA_BATCH;
  f16* mV = ws + MV_OFF + (size_t)b * MV_BATCH;
  f16* tl = ws + TL_OFF + (size_t)b * TL_BATCH;

  const int c  = c0 + r;
  const int hq = h0 + q * 16;
  if (hq < HW_) {
    const float* src = x + (size_t)b * (C_ * HW_) + (size_t)c * HW_ + hq;
    float f[16];
#pragma unroll
    for (int j = 0; j < 4; ++j) ((float4*)f)[j] = ((const float4*)src)[j];
    f16 h[16];
#pragma unroll
    for (int j = 0; j < 16; ++j) h[j] = (f16)f[j];
    const int p = c >> 5, row = c & 31, kt = hq >> 4;
    f16* d0 = mA + ((size_t)p * 49 + kt) * 512 + row * 8;
    *(half8*)d0         = *(half8*)h;        // k-half 0 -> lanes 0..31
    *(half8*)(d0 + 256) = *(half8*)(h + 8);  // k-half 1 -> lanes 32..63
    *(half8*)&lt[r][q * 16]     = *(half8*)h;
    *(half8*)&lt[r][q * 16 + 8] = *(half8*)(h + 8);
  }
  __syncthreads();
  // transposed side: d = hw, kv = c
  const int d = h0 + r;
  if (d < HW_) {
    f16 g[16];
#pragma unroll
    for (int j = 0; j < 16; ++j) g[j] = lt[q * 16 + j][r];
    const int kt = (c0 >> 4) + q;
    if (d < 768) {
      const int pd = d >> 5, dc = d & 31;
      f16* e0 = mV + ((size_t)pd * 64 + kt) * 512 + dc * 8;
      *(half8*)e0         = *(half8*)g;
      *(half8*)(e0 + 256) = *(half8*)(g + 8);
    } else {
      f16* e0 = tl + kt * 256 + (d & 15) * 8;
      *(half8*)e0         = *(half8*)g;
      *(half8*)(e0 + 128) = *(half8*)(g + 8);
    }
  }
}

// ---------------------------------------------------------------------------
// Main: 32x32x16 MFMA both phases; 1-deep register ping-pong prefetch.
// ---------------------------------------------------------------------------
__global__ __launch_bounds__(1024, 4)
void chanattn_main(const float* __restrict__ x, const f16* __restrict__ ws,
                   float* __restrict__ out) {
  __shared__ f16 Pl[BQ * C_];   // 128 KiB
  char* Pb = (char*)Pl;

  const int bi   = blockIdx.x;
  const int slot = bi >> 3;
  const int b    = ((slot >> 4) << 3) | (bi & 7);   // same-batch WGs share an XCD
  const int rb   = slot & 15;
  const int q0   = rb * BQ;

  const int tid  = threadIdx.x;
  const int w    = tid >> 6;    // 0..15
  const int lane = tid & 63;
  const int l31  = lane & 31;
  const int lh   = lane >> 5;   // k-half

  const f16* mA = ws + (size_t)b * MA_BATCH;
  const f16* mV = ws + MV_OFF + (size_t)b * MV_BATCH;
  const f16* tl = ws + TL_OFF + (size_t)b * TL_BATCH;

  // ---------------- Phase 1: raw scores S = M[q-rows] . M^T ----------------
  {
    const f16* aB0 = mA + ((size_t)(rb * 2 + 0) * 49) * 512 + lane * 8;
    const f16* aB1 = mA + ((size_t)(rb * 2 + 1) * 49) * 512 + lane * 8;
    const f16* bB0 = mA + ((size_t)(w * 2 + 0) * 49) * 512 + lane * 8;
    const f16* bB1 = mA + ((size_t)(w * 2 + 1) * 49) * 512 + lane * 8;

#define LD1(kt, A, Bv) do {                                 \
  A[0]  = *(const half8*)(aB0 + (size_t)(kt) * 512);        \
  A[1]  = *(const half8*)(aB1 + (size_t)(kt) * 512);        \
  Bv[0] = *(const half8*)(bB0 + (size_t)(kt) * 512);        \
  Bv[1] = *(const half8*)(bB1 + (size_t)(kt) * 512);        \
} while (0)

#define MM4(A, Bv) do {                                                        \
  acc00 = __builtin_amdgcn_mfma_f32_32x32x16_f16(A[0], Bv[0], acc00, 0, 0, 0); \
  acc01 = __builtin_amdgcn_mfma_f32_32x32x16_f16(A[0], Bv[1], acc01, 0, 0, 0); \
  acc10 = __builtin_amdgcn_mfma_f32_32x32x16_f16(A[1], Bv[0], acc10, 0, 0, 0); \
  acc11 = __builtin_amdgcn_mfma_f32_32x32x16_f16(A[1], Bv[1], acc11, 0, 0, 0); \
} while (0)

    f32x16 acc00 = {}, acc01 = {}, acc10 = {}, acc11 = {};
    half8 A0[2], B0[2], A1[2], B1[2];
    LD1(0, A0, B0);
    for (int kt = 0; kt < 48; kt += 2) {      // 49 kt total; 48 handled here
      LD1(kt + 1, A1, B1);
      MM4(A0, B0);
      LD1(kt + 2, A0, B0);                    // kt+2 <= 48 always valid
      MM4(A1, B1);
    }
    MM4(A0, B0);                               // kt = 48

    // write raw f16 scores -> P (XOR swizzle (row&7)<<4)
#pragma unroll
    for (int reg = 0; reg < 16; ++reg) {
      const int rloc = (reg & 3) + 8 * (reg >> 2) + 4 * lh;  // C/D row mapping
#define PSTORE(rowv, colv, val) do {                          \
  const int row_ = (rowv); int byte_ = row_ * 2048 + (colv) * 2; \
  byte_ ^= (row_ & 7) << 4;                                   \
  *(f16*)(Pb + byte_) = (f16)(val);                           \
} while (0)
      PSTORE(rloc,      w * 64 + l31,      acc00[reg]);
      PSTORE(rloc,      w * 64 + 32 + l31, acc01[reg]);
      PSTORE(32 + rloc, w * 64 + l31,      acc10[reg]);
      PSTORE(32 + rloc, w * 64 + 32 + l31, acc11[reg]);
    }
  }
  __syncthreads();

  // ---------------- softmax, rows w*4..w*4+3 (lane-consecutive 16B) ----------------
  {
    const float ksc = 0.045084223f;   // log2(e)/32
    for (int rr = 0; rr < 4; ++rr) {
      const int row = w * 4 + rr;
      const int sw  = (row & 7) << 4;
      char* rbase = Pb + row * 2048;
      const int p0 = (lane * 16) ^ sw;
      half8 v0 = *(half8*)(rbase + p0);
      half8 v1 = *(half8*)(rbase + 1024 + p0);
      float f[16];
#pragma unroll
      for (int e = 0; e < 8; ++e) { f[e] = (float)v0[e]; f[e+8] = (float)v1[e]; }
      float mx = f[0];
#pragma unroll
      for (int e = 1; e < 16; ++e) mx = fmaxf(mx, f[e]);
      for (int d = 1; d < 64; d <<= 1) mx = fmaxf(mx, __shfl_xor(mx, d));
      float sum = 0.f;
#pragma unroll
      for (int e = 0; e < 16; ++e) { f[e] = exp2f((f[e] - mx) * ksc); sum += f[e]; }
      for (int d = 1; d < 64; d <<= 1) sum += __shfl_xor(sum, d);
      const float inv = 1.f / sum;
#pragma unroll
      for (int e = 0; e < 8; ++e) { v0[e] = (f16)(f[e]*inv); v1[e] = (f16)(f[e+8]*inv); }
      *(half8*)(rbase + p0) = v0;
      *(half8*)(rbase + 1024 + p0) = v1;
    }
  }
  __syncthreads();

  // ---------------- Phase 2: y = P . V ; out = x + y ----------------
  {
    const bool vok = (l31 < 16);     // valid lanes for the compact tail panel

#define LDPA(kt, pa) do {                                       \
  _Pragma("unroll") for (int ra_ = 0; ra_ < 2; ++ra_) {         \
    const int row_ = ra_ * 32 + l31;                            \
    int byte_ = row_ * 2048 + (kt) * 32 + lh * 16;              \
    byte_ ^= (row_ & 7) << 4;                                   \
    pa[ra_] = *(const half8*)(Pb + byte_); }                    \
} while (0)

#define LDVF(kt, v) do { v = *(const half8*)(vB + (size_t)(kt) * 512 + lane * 8); } while (0)
#define LDVT(kt, v) do {                                        \
  half8 z_ = {};                                                \
  if (vok) z_ = *(const half8*)(tl + (kt) * 256 + lh * 128 + l31 * 8); \
  v = z_;                                                       \
} while (0)

#define PV_PANEL(LDV_) do {                                                         \
  f32x16 p0 = {}, p1 = {};                                                          \
  half8 pa0[2], pa1[2], vv0, vv1;                                                   \
  LDPA(0, pa0); LDV_(0, vv0);                                                       \
  for (int kt = 0; kt < 64; kt += 2) {                                              \
    LDPA(kt + 1, pa1); LDV_(kt + 1, vv1);                                           \
    p0 = __builtin_amdgcn_mfma_f32_32x32x16_f16(pa0[0], vv0, p0, 0, 0, 0);          \
    p1 = __builtin_amdgcn_mfma_f32_32x32x16_f16(pa0[1], vv0, p1, 0, 0, 0);          \
    if (kt + 2 < 64) { LDPA(kt + 2, pa0); LDV_(kt + 2, vv0); }                      \
    p0 = __builtin_amdgcn_mfma_f32_32x32x16_f16(pa1[0], vv1, p0, 0, 0, 0);          \
    p1 = __builtin_amdgcn_mfma_f32_32x32x16_f16(pa1[1], vv1, p1, 0, 0, 0);          \
  }                                                                                 \
  const int dd = pd * 32 + l31;                                                     \
  if (dd < HW_) {                                                                   \
    _Pragma("unroll") for (int reg_ = 0; reg_ < 16; ++reg_) {                       \
      const int rl_ = (reg_ & 3) + 8 * (reg_ >> 2) + 4 * lh;                        \
      size_t i0_ = (size_t)(b * C_ + q0 + rl_) * HW_ + dd;                          \
      size_t i1_ = (size_t)(b * C_ + q0 + 32 + rl_) * HW_ + dd;                     \
      out[i0_] = x[i0_] + p0[reg_];                                                 \
      out[i1_] = x[i1_] + p1[reg_];                                                 \
    }                                                                               \
  }                                                                                 \
} while (0)

    for (int si = 0; si < 2; ++si) {
      const int pd = w + 16 * si;
      if (pd >= 25) break;
      if (pd < 24) {
        const f16* vB = mV + (size_t)pd * 64 * 512;
        PV_PANEL(LDVF);
      } else {
        PV_PANEL(LDVT);
      }
    }
  }
}

// ---------------------------------------------------------------------------
// Fallback (round-1 kernel): only if ws too small.
// ---------------------------------------------------------------------------
__device__ __forceinline__ half8 pack8(const float4& a, const float4& b) {
  half8 r;
  r[0]=(f16)a.x; r[1]=(f16)a.y; r[2]=(f16)a.z; r[3]=(f16)a.w;
  r[4]=(f16)b.x; r[5]=(f16)b.y; r[6]=(f16)b.z; r[7]=(f16)b.w;
  return r;
}

__global__ __launch_bounds__(512, 2)
void chanattn_fallback(const float* __restrict__ x, float* __restrict__ out) {
  __shared__ f16 Pl[BQ * C_];
  const int bi   = blockIdx.x;
  const int slot = bi >> 3;
  const int b    = ((slot >> 4) << 3) | (bi & 7);
  const int rb   = slot & 15;
  const int q0   = rb * BQ;
  const int tid  = threadIdx.x;
  const int w    = tid >> 6;
  const int lane = tid & 63;
  const int l15  = lane & 15;
  const int l4   = lane >> 4;
  const float* mb = x + (size_t)b * (C_ * HW_);
  char* Pb = (char*)Pl;
  {
    const int cw = w * 128;
    for (int tile = 0; tile < 2; ++tile) {
      const int c0 = cw + tile * 64;
      f32x4 acc[4][4] = {};
      for (int kc = 0; kc < 25; ++kc) {
        const int k0 = kc * 32 + l4 * 8;
        const bool ok = (k0 < HW_);
        half8 afr[4], bfr[4];
#pragma unroll
        for (int rf = 0; rf < 4; ++rf) {
          if (ok) { const float4* p = (const float4*)(mb + (q0 + rf*16 + l15) * HW_ + k0); afr[rf] = pack8(p[0], p[1]); }
          else {
#pragma unroll
            for (int e = 0; e < 8; ++e) afr[rf][e] = (f16)0.f; }
        }
#pragma unroll
        for (int cf = 0; cf < 4; ++cf) {
          if (ok) { const float4* p = (const float4*)(mb + (c0 + cf*16 + l15) * HW_ + k0); bfr[cf] = pack8(p[0], p[1]); }
          else {
#pragma unroll
            for (int e = 0; e < 8; ++e) bfr[cf][e] = (f16)0.f; }
        }
#pragma unroll
        for (int rf = 0; rf < 4; ++rf)
#pragma unroll
          for (int cf = 0; cf < 4; ++cf)
            acc[rf][cf] = __builtin_amdgcn_mfma_f32_16x16x32_f16(afr[rf], bfr[cf], acc[rf][cf], 0, 0, 0);
      }
#pragma unroll
      for (int rf = 0; rf < 4; ++rf)
#pragma unroll
        for (int cf = 0; cf < 4; ++cf)
#pragma unroll
          for (int r = 0; r < 4; ++r) {
            const int row = rf*16 + l4*4 + r;
            const int col = c0 + cf*16 + l15;
            int byte = row*2048 + col*2;
            byte ^= (row & 7) << 4;
            *(f16*)(Pb + byte) = (f16)acc[rf][cf][r];
          }
    }
  }
  __syncthreads();
  {
    const float ksc = 0.045084223f;
    for (int rr = 0; rr < 8; ++rr) {
      const int row = w*8 + rr;
      const int sw  = (row & 7) << 4;
      char* rbase = Pb + row*2048;
      const int p0 = (lane * 16) ^ sw;
      half8 v0 = *(half8*)(rbase + p0);
      half8 v1 = *(half8*)(rbase + 1024 + p0);
      float f[16];
#pragma unroll
      for (int e = 0; e < 8; ++e) { f[e] = (float)v0[e]; f[e+8] = (float)v1[e]; }
      float mx = f[0];
#pragma unroll
      for (int e = 1; e < 16; ++e) mx = fmaxf(mx, f[e]);
      for (int d = 1; d < 64; d <<= 1) mx = fmaxf(mx, __shfl_xor(mx, d));
      float sum = 0.f;
#pragma unroll
      for (int e = 0; e < 16; ++e) { f[e] = exp2f((f[e] - mx) * ksc); sum += f[e]; }
      for (int d = 1; d < 64; d <<= 1) sum += __shfl_xor(sum, d);
      const float inv = 1.f / sum;
#pragma unroll
      for (int e = 0; e < 8; ++e) { v0[e] = (f16)(f[e]*inv); v1[e] = (f16)(f[e+8]*inv); }
      *(half8*)(rbase + p0) = v0;
      *(half8*)(rbase + 1024 + p0) = v1;
    }
  }
  __syncthreads();
  {
    f32x4 acc[7][4] = {};
    for (int t = 0; t < 16; ++t) {
      half8 afr[4][2];
#pragma unroll
      for (int rf = 0; rf < 4; ++rf)
#pragma unroll
        for (int kf = 0; kf < 2; ++kf) {
          const int row = rf*16 + l15;
          int byte = row*2048 + t*128 + kf*64 + l4*16;
          byte ^= (row & 7) << 4;
          afr[rf][kf] = *(half8*)(Pb + byte);
        }
#pragma unroll
      for (int si = 0; si < 7; ++si) {
        const int s = w + 8*si;
        if (s < 49) {
          const int d = s*16 + l15;
#pragma unroll
          for (int kf = 0; kf < 2; ++kf) {
            const int kv = t*64 + kf*32 + l4*8;
            half8 bfr;
#pragma unroll
            for (int e = 0; e < 8; ++e) bfr[e] = (f16)mb[(kv + e) * HW_ + d];
#pragma unroll
            for (int rf = 0; rf < 4; ++rf)
              acc[si][rf] = __builtin_amdgcn_mfma_f32_16x16x32_f16(afr[rf][kf], bfr, acc[si][rf], 0, 0, 0);
          }
        }
      }
    }
#pragma unroll
    for (int si = 0; si < 7; ++si) {
      const int s = w + 8*si;
      if (s < 49) {
        const int d = s*16 + l15;
#pragma unroll
        for (int rf = 0; rf < 4; ++rf)
#pragma unroll
          for (int r = 0; r < 4; ++r) {
            const size_t idx = (size_t)(b*C_ + q0 + rf*16 + l4*4 + r) * HW_ + d;
            out[idx] = x[idx] + acc[si][rf][r];
          }
      }
    }
  }
}

extern "C" void kernel_launch(void* const* d_in, const int* in_sizes, int n_in,
                              void* d_out, int out_size, void* d_ws, size_t ws_size,
                              hipStream_t stream) {
  const float* x = (const float*)d_in[0];
  float* out = (float*)d_out;
  const size_t need = (TL_OFF + 32ull * TL_BATCH) * 2;   // 102,760,448 B
  if (ws_size >= need) {
    f16* ws = (f16*)d_ws;
    prep_kernel<<<dim3(32 * 16 * 13), dim3(256), 0, stream>>>(x, ws);
    chanattn_main<<<dim3(512), dim3(1024), 0, stream>>>(x, ws, out);
  } else {
    chanattn_fallback<<<dim3(512), dim3(512), 0, stream>>>(x, out);
  }
}

// Round 9
// 478.487 us; speedup vs baseline: 2.4912x; 1.2780x over previous
//
#include <hip/hip_runtime.h>

typedef _Float16 f16;
typedef f16  half8  __attribute__((ext_vector_type(8)));
typedef float f32x4  __attribute__((ext_vector_type(4)));
typedef float f32x16 __attribute__((ext_vector_type(16)));

#define B_   32
#define C_   1024
#define HW_  784
#define BQ   32

// Fragment-packed ws layouts for 32x32x16 MFMA (f16 elems) — same as r8:
//  mA32 [b][p=c>>5][kt=hw>>4 (49)][lane*8] : row=lane&31 -> c=p*32+row, k=kt*16+(lane>>5)*8+e
//  mV32 [b][pd=d>>5 (24)][kt=kv>>4 (64)][lane*8] : col=lane&31 -> d, k=kv
//  tl   [b][kt (64)][256] : compact d=768..783 panel; valid lanes (lane&31)<16
#define MA_BATCH  802816ull      // 32*49*512
#define MV_OFF    25690112ull    // 32*MA_BATCH
#define MV_BATCH  786432ull      // 24*64*512
#define TL_OFF    50855936ull    // MV_OFF + 32*MV_BATCH
#define TL_BATCH  16384ull       // 64*256
// total = (TL_OFF + 32*TL_BATCH)*2 = 102,760,448 bytes (exact ws fit)

// ---------------------------------------------------------------------------
// Prep: fragment-pack x into mA32 / mV32 / tl (f32 -> f16).  (unchanged r8)
// ---------------------------------------------------------------------------
__global__ __launch_bounds__(256)
void prep_kernel(const float* __restrict__ x, f16* __restrict__ ws) {
  __shared__ f16 lt[64][72];
  const int bi = blockIdx.x;               // b*208 + ct*13 + ht
  const int ht = bi % 13;
  const int ct = (bi / 13) & 15;
  const int b  = bi / 208;
  const int h0 = ht * 64, c0 = ct * 64;
  const int t = threadIdx.x, r = t >> 2, q = t & 3;

  f16* mA = ws + (size_t)b * MA_BATCH;
  f16* mV = ws + MV_OFF + (size_t)b * MV_BATCH;
  f16* tl = ws + TL_OFF + (size_t)b * TL_BATCH;

  const int c  = c0 + r;
  const int hq = h0 + q * 16;
  if (hq < HW_) {
    const float* src = x + (size_t)b * (C_ * HW_) + (size_t)c * HW_ + hq;
    float f[16];
#pragma unroll
    for (int j = 0; j < 4; ++j) ((float4*)f)[j] = ((const float4*)src)[j];
    f16 h[16];
#pragma unroll
    for (int j = 0; j < 16; ++j) h[j] = (f16)f[j];
    const int p = c >> 5, row = c & 31, kt = hq >> 4;
    f16* d0 = mA + ((size_t)p * 49 + kt) * 512 + row * 8;
    *(half8*)d0         = *(half8*)h;        // k-half 0 -> lanes 0..31
    *(half8*)(d0 + 256) = *(half8*)(h + 8);  // k-half 1 -> lanes 32..63
    *(half8*)&lt[r][q * 16]     = *(half8*)h;
    *(half8*)&lt[r][q * 16 + 8] = *(half8*)(h + 8);
  }
  __syncthreads();
  // transposed side: d = hw, kv = c
  const int d = h0 + r;
  if (d < HW_) {
    f16 g[16];
#pragma unroll
    for (int j = 0; j < 16; ++j) g[j] = lt[q * 16 + j][r];
    const int kt = (c0 >> 4) + q;
    if (d < 768) {
      const int pd = d >> 5, dc = d & 31;
      f16* e0 = mV + ((size_t)pd * 64 + kt) * 512 + dc * 8;
      *(half8*)e0         = *(half8*)g;
      *(half8*)(e0 + 256) = *(half8*)(g + 8);
    } else {
      f16* e0 = tl + kt * 256 + (d & 15) * 8;
      *(half8*)e0         = *(half8*)g;
      *(half8*)(e0 + 128) = *(half8*)(g + 8);
    }
  }
}

// ---------------------------------------------------------------------------
// Main: BQ=32, 512 threads (8 waves), 64 KiB P -> 2 WG/CU.
// 32x32x16 MFMA both phases; 1-deep register ping-pong prefetch.
// ---------------------------------------------------------------------------
__global__ __launch_bounds__(512, 4)
void chanattn_main(const float* __restrict__ x, const f16* __restrict__ ws,
                   float* __restrict__ out) {
  __shared__ f16 Pl[BQ * C_];   // 64 KiB
  char* Pb = (char*)Pl;

  // grid 1024 = 32 batches x 32 row-blocks; same-batch WGs share an XCD
  const int bi = blockIdx.x;
  const int b  = ((bi >> 8) << 3) | (bi & 7);
  const int rb = (bi >> 3) & 31;
  const int q0 = rb * BQ;

  const int tid  = threadIdx.x;
  const int w    = tid >> 6;    // 0..7
  const int lane = tid & 63;
  const int l31  = lane & 31;
  const int lh   = lane >> 5;   // k-half

  const f16* mA = ws + (size_t)b * MA_BATCH;
  const f16* mV = ws + MV_OFF + (size_t)b * MV_BATCH;
  const f16* tl = ws + TL_OFF + (size_t)b * TL_BATCH;

  // ---------------- Phase 1: S = M[q0..q0+31] . M^T ----------------
  {
    const f16* aB = mA + (size_t)rb * 49 * 512 + lane * 8;
    const f16* bB0 = mA + (size_t)(w * 4 + 0) * 49 * 512 + lane * 8;
    const f16* bB1 = mA + (size_t)(w * 4 + 1) * 49 * 512 + lane * 8;
    const f16* bB2 = mA + (size_t)(w * 4 + 2) * 49 * 512 + lane * 8;
    const f16* bB3 = mA + (size_t)(w * 4 + 3) * 49 * 512 + lane * 8;

#define LD1(kt, Av, Bv) do {                                \
  Av    = *(const half8*)(aB  + (size_t)(kt) * 512);        \
  Bv[0] = *(const half8*)(bB0 + (size_t)(kt) * 512);        \
  Bv[1] = *(const half8*)(bB1 + (size_t)(kt) * 512);        \
  Bv[2] = *(const half8*)(bB2 + (size_t)(kt) * 512);        \
  Bv[3] = *(const half8*)(bB3 + (size_t)(kt) * 512);        \
} while (0)

#define MM4(Av, Bv) do {                                                        \
  acc[0] = __builtin_amdgcn_mfma_f32_32x32x16_f16(Av, Bv[0], acc[0], 0, 0, 0);  \
  acc[1] = __builtin_amdgcn_mfma_f32_32x32x16_f16(Av, Bv[1], acc[1], 0, 0, 0);  \
  acc[2] = __builtin_amdgcn_mfma_f32_32x32x16_f16(Av, Bv[2], acc[2], 0, 0, 0);  \
  acc[3] = __builtin_amdgcn_mfma_f32_32x32x16_f16(Av, Bv[3], acc[3], 0, 0, 0);  \
} while (0)

    f32x16 acc[4] = {};
    half8 A0, A1, B0[4], B1[4];
    LD1(0, A0, B0);
    for (int kt = 0; kt < 48; kt += 2) {      // 49 kt total
      LD1(kt + 1, A1, B1);
      MM4(A0, B0);
      LD1(kt + 2, A0, B0);                    // kt+2 <= 48
      MM4(A1, B1);
    }
    MM4(A0, B0);                               // kt = 48

    // write raw f16 scores -> P (XOR swizzle (row&7)<<4)
#pragma unroll
    for (int reg = 0; reg < 16; ++reg) {
      const int rloc = (reg & 3) + 8 * (reg >> 2) + 4 * lh;  // C/D row in 0..31
#pragma unroll
      for (int cf = 0; cf < 4; ++cf) {
        const int col = (w * 4 + cf) * 32 + l31;
        int byte = rloc * 2048 + col * 2;
        byte ^= (rloc & 7) << 4;
        *(f16*)(Pb + byte) = (f16)acc[cf][reg];
      }
    }
  }
  __syncthreads();

  // ---------------- softmax, rows w*4..w*4+3 (lane-consecutive 16B) ----------------
  {
    const float ksc = 0.045084223f;   // log2(e)/32
    for (int rr = 0; rr < 4; ++rr) {
      const int row = w * 4 + rr;
      const int sw  = (row & 7) << 4;
      char* rbase = Pb + row * 2048;
      const int p0 = (lane * 16) ^ sw;
      half8 v0 = *(half8*)(rbase + p0);
      half8 v1 = *(half8*)(rbase + 1024 + p0);
      float f[16];
#pragma unroll
      for (int e = 0; e < 8; ++e) { f[e] = (float)v0[e]; f[e+8] = (float)v1[e]; }
      float mx = f[0];
#pragma unroll
      for (int e = 1; e < 16; ++e) mx = fmaxf(mx, f[e]);
      for (int d = 1; d < 64; d <<= 1) mx = fmaxf(mx, __shfl_xor(mx, d));
      float sum = 0.f;
#pragma unroll
      for (int e = 0; e < 16; ++e) { f[e] = exp2f((f[e] - mx) * ksc); sum += f[e]; }
      for (int d = 1; d < 64; d <<= 1) sum += __shfl_xor(sum, d);
      const float inv = 1.f / sum;
#pragma unroll
      for (int e = 0; e < 8; ++e) { v0[e] = (f16)(f[e]*inv); v1[e] = (f16)(f[e+8]*inv); }
      *(half8*)(rbase + p0) = v0;
      *(half8*)(rbase + 1024 + p0) = v1;
    }
  }
  __syncthreads();

  // ---------------- Phase 2: y = P . V ; out = x + y ----------------
  {
    const bool vok = (l31 < 16);     // valid lanes for compact tail panel

#define LDPA(kt, pav) do {                                  \
  int byte_ = l31 * 2048 + (kt) * 32 + lh * 16;             \
  byte_ ^= (l31 & 7) << 4;                                  \
  pav = *(const half8*)(Pb + byte_);                        \
} while (0)

#define LDVF(kt, v) do { v = *(const half8*)(vB + (size_t)(kt) * 512 + lane * 8); } while (0)
#define LDVT(kt, v) do {                                    \
  half8 z_ = {};                                            \
  if (vok) z_ = *(const half8*)(tl + (kt) * 256 + lh * 128 + l31 * 8); \
  v = z_;                                                   \
} while (0)

#define PV_PANEL(LDV_) do {                                                         \
  f32x16 p0 = {};                                                                   \
  half8 pa0, pa1, vv0, vv1;                                                         \
  LDPA(0, pa0); LDV_(0, vv0);                                                       \
  for (int kt = 0; kt < 64; kt += 2) {                                              \
    LDPA(kt + 1, pa1); LDV_(kt + 1, vv1);                                           \
    p0 = __builtin_amdgcn_mfma_f32_32x32x16_f16(pa0, vv0, p0, 0, 0, 0);             \
    if (kt + 2 < 64) { LDPA(kt + 2, pa0); LDV_(kt + 2, vv0); }                      \
    p0 = __builtin_amdgcn_mfma_f32_32x32x16_f16(pa1, vv1, p0, 0, 0, 0);             \
  }                                                                                 \
  const int dd = pd * 32 + l31;                                                     \
  if (dd < HW_) {                                                                   \
    _Pragma("unroll") for (int reg_ = 0; reg_ < 16; ++reg_) {                       \
      const int rl_ = (reg_ & 3) + 8 * (reg_ >> 2) + 4 * lh;                        \
      const size_t i0_ = (size_t)(b * C_ + q0 + rl_) * HW_ + dd;                    \
      out[i0_] = x[i0_] + p0[reg_];                                                 \
    }                                                                               \
  }                                                                                 \
} while (0)

    for (int si = 0; si < 4; ++si) {
      const int pd = w + 8 * si;
      if (pd >= 25) break;                    // wave-uniform
      if (pd < 24) {
        const f16* vB = mV + (size_t)pd * 64 * 512;
        PV_PANEL(LDVF);
      } else {
        PV_PANEL(LDVT);
      }
    }
  }
}

// ---------------------------------------------------------------------------
// Fallback (round-1 kernel): only if ws too small.
// ---------------------------------------------------------------------------
__device__ __forceinline__ half8 pack8(const float4& a, const float4& b) {
  half8 r;
  r[0]=(f16)a.x; r[1]=(f16)a.y; r[2]=(f16)a.z; r[3]=(f16)a.w;
  r[4]=(f16)b.x; r[5]=(f16)b.y; r[6]=(f16)b.z; r[7]=(f16)b.w;
  return r;
}

__global__ __launch_bounds__(512, 2)
void chanattn_fallback(const float* __restrict__ x, float* __restrict__ out) {
  __shared__ f16 Pl[64 * C_];
  const int bi   = blockIdx.x;
  const int slot = bi >> 3;
  const int b    = ((slot >> 4) << 3) | (bi & 7);
  const int rb   = slot & 15;
  const int q0   = rb * 64;
  const int tid  = threadIdx.x;
  const int w    = tid >> 6;
  const int lane = tid & 63;
  const int l15  = lane & 15;
  const int l4   = lane >> 4;
  const float* mb = x + (size_t)b * (C_ * HW_);
  char* Pb = (char*)Pl;
  {
    const int cw = w * 128;
    for (int tile = 0; tile < 2; ++tile) {
      const int c0 = cw + tile * 64;
      f32x4 acc[4][4] = {};
      for (int kc = 0; kc < 25; ++kc) {
        const int k0 = kc * 32 + l4 * 8;
        const bool ok = (k0 < HW_);
        half8 afr[4], bfr[4];
#pragma unroll
        for (int rf = 0; rf < 4; ++rf) {
          if (ok) { const float4* p = (const float4*)(mb + (q0 + rf*16 + l15) * HW_ + k0); afr[rf] = pack8(p[0], p[1]); }
          else {
#pragma unroll
            for (int e = 0; e < 8; ++e) afr[rf][e] = (f16)0.f; }
        }
#pragma unroll
        for (int cf = 0; cf < 4; ++cf) {
          if (ok) { const float4* p = (const float4*)(mb + (c0 + cf*16 + l15) * HW_ + k0); bfr[cf] = pack8(p[0], p[1]); }
          else {
#pragma unroll
            for (int e = 0; e < 8; ++e) bfr[cf][e] = (f16)0.f; }
        }
#pragma unroll
        for (int rf = 0; rf < 4; ++rf)
#pragma unroll
          for (int cf = 0; cf < 4; ++cf)
            acc[rf][cf] = __builtin_amdgcn_mfma_f32_16x16x32_f16(afr[rf], bfr[cf], acc[rf][cf], 0, 0, 0);
      }
#pragma unroll
      for (int rf = 0; rf < 4; ++rf)
#pragma unroll
        for (int cf = 0; cf < 4; ++cf)
#pragma unroll
          for (int r = 0; r < 4; ++r) {
            const int row = rf*16 + l4*4 + r;
            const int col = c0 + cf*16 + l15;
            int byte = row*2048 + col*2;
            byte ^= (row & 7) << 4;
            *(f16*)(Pb + byte) = (f16)acc[rf][cf][r];
          }
    }
  }
  __syncthreads();
  {
    const float ksc = 0.045084223f;
    for (int rr = 0; rr < 8; ++rr) {
      const int row = w*8 + rr;
      const int sw  = (row & 7) << 4;
      char* rbase = Pb + row*2048;
      const int p0 = (lane * 16) ^ sw;
      half8 v0 = *(half8*)(rbase + p0);
      half8 v1 = *(half8*)(rbase + 1024 + p0);
      float f[16];
#pragma unroll
      for (int e = 0; e < 8; ++e) { f[e] = (float)v0[e]; f[e+8] = (float)v1[e]; }
      float mx = f[0];
#pragma unroll
      for (int e = 1; e < 16; ++e) mx = fmaxf(mx, f[e]);
      for (int d = 1; d < 64; d <<= 1) mx = fmaxf(mx, __shfl_xor(mx, d));
      float sum = 0.f;
#pragma unroll
      for (int e = 0; e < 16; ++e) { f[e] = exp2f((f[e] - mx) * ksc); sum += f[e]; }
      for (int d = 1; d < 64; d <<= 1) sum += __shfl_xor(sum, d);
      const float inv = 1.f / sum;
#pragma unroll
      for (int e = 0; e < 8; ++e) { v0[e] = (f16)(f[e]*inv); v1[e] = (f16)(f[e+8]*inv); }
      *(half8*)(rbase + p0) = v0;
      *(half8*)(rbase + 1024 + p0) = v1;
    }
  }
  __syncthreads();
  {
    f32x4 acc[7][4] = {};
    for (int t = 0; t < 16; ++t) {
      half8 afr[4][2];
#pragma unroll
      for (int rf = 0; rf < 4; ++rf)
#pragma unroll
        for (int kf = 0; kf < 2; ++kf) {
          const int row = rf*16 + l15;
          int byte = row*2048 + t*128 + kf*64 + l4*16;
          byte ^= (row & 7) << 4;
          afr[rf][kf] = *(half8*)(Pb + byte);
        }
#pragma unroll
      for (int si = 0; si < 7; ++si) {
        const int s = w + 8*si;
        if (s < 49) {
          const int d = s*16 + l15;
#pragma unroll
          for (int kf = 0; kf < 2; ++kf) {
            const int kv = t*64 + kf*32 + l4*8;
            half8 bfr;
#pragma unroll
            for (int e = 0; e < 8; ++e) bfr[e] = (f16)mb[(kv + e) * HW_ + d];
#pragma unroll
            for (int rf = 0; rf < 4; ++rf)
              acc[si][rf] = __builtin_amdgcn_mfma_f32_16x16x32_f16(afr[rf][kf], bfr, acc[si][rf], 0, 0, 0);
          }
        }
      }
    }
#pragma unroll
    for (int si = 0; si < 7; ++si) {
      const int s = w + 8*si;
      if (s < 49) {
        const int d = s*16 + l15;
#pragma unroll
        for (int rf = 0; rf < 4; ++rf)
#pragma unroll
          for (int r = 0; r < 4; ++r) {
            const size_t idx = (size_t)(b*C_ + q0 + rf*16 + l4*4 + r) * HW_ + d;
            out[idx] = x[idx] + acc[si][rf][r];
          }
      }
    }
  }
}

extern "C" void kernel_launch(void* const* d_in, const int* in_sizes, int n_in,
                              void* d_out, int out_size, void* d_ws, size_t ws_size,
                              hipStream_t stream) {
  const float* x = (const float*)d_in[0];
  float* out = (float*)d_out;
  const size_t need = (TL_OFF + 32ull * TL_BATCH) * 2;   // 102,760,448 B
  if (ws_size >= need) {
    f16* ws = (f16*)d_ws;
    prep_kernel<<<dim3(32 * 16 * 13), dim3(256), 0, stream>>>(x, ws);
    chanattn_main<<<dim3(1024), dim3(512), 0, stream>>>(x, ws, out);
  } else {
    chanattn_fallback<<<dim3(512), dim3(512), 0, stream>>>(x, out);
  }
}

// Round 10
// 403.871 us; speedup vs baseline: 2.9514x; 1.1848x over previous
//
#include <hip/hip_runtime.h>

typedef _Float16 f16;
typedef f16  half8  __attribute__((ext_vector_type(8)));
typedef float f32x4  __attribute__((ext_vector_type(4)));
typedef float f32x16 __attribute__((ext_vector_type(16)));

#define B_   32
#define C_   1024
#define HW_  784
#define BQ   64

// Fragment-packed ws layouts for 32x32x16 MFMA (f16 elems) — same as r8:
//  mA32 [b][p=c>>5][kt=hw>>4 (49)][lane*8] : row=lane&31 -> c=p*32+row, k=kt*16+(lane>>5)*8+e
//  mV32 [b][pd=d>>5 (24)][kt=kv>>4 (64)][lane*8] : col=lane&31 -> d, k=kv
//  tl   [b][kt (64)][256] : compact d=768..783 panel; valid lanes (lane&31)<16
#define MA_BATCH  802816ull      // 32*49*512
#define MV_OFF    25690112ull    // 32*MA_BATCH
#define MV_BATCH  786432ull      // 24*64*512
#define TL_OFF    50855936ull    // MV_OFF + 32*MV_BATCH
#define TL_BATCH  16384ull       // 64*256
// total = (TL_OFF + 32*TL_BATCH)*2 = 102,760,448 bytes (exact ws fit)

// ---------------------------------------------------------------------------
// Prep: fragment-pack x into mA32 / mV32 / tl (f32 -> f16).  (unchanged)
// ---------------------------------------------------------------------------
__global__ __launch_bounds__(256)
void prep_kernel(const float* __restrict__ x, f16* __restrict__ ws) {
  __shared__ f16 lt[64][72];
  const int bi = blockIdx.x;               // b*208 + ct*13 + ht
  const int ht = bi % 13;
  const int ct = (bi / 13) & 15;
  const int b  = bi / 208;
  const int h0 = ht * 64, c0 = ct * 64;
  const int t = threadIdx.x, r = t >> 2, q = t & 3;

  f16* mA = ws + (size_t)b * MA_BATCH;
  f16* mV = ws + MV_OFF + (size_t)b * MV_BATCH;
  f16* tl = ws + TL_OFF + (size_t)b * TL_BATCH;

  const int c  = c0 + r;
  const int hq = h0 + q * 16;
  if (hq < HW_) {
    const float* src = x + (size_t)b * (C_ * HW_) + (size_t)c * HW_ + hq;
    float f[16];
#pragma unroll
    for (int j = 0; j < 4; ++j) ((float4*)f)[j] = ((const float4*)src)[j];
    f16 h[16];
#pragma unroll
    for (int j = 0; j < 16; ++j) h[j] = (f16)f[j];
    const int p = c >> 5, row = c & 31, kt = hq >> 4;
    f16* d0 = mA + ((size_t)p * 49 + kt) * 512 + row * 8;
    *(half8*)d0         = *(half8*)h;        // k-half 0 -> lanes 0..31
    *(half8*)(d0 + 256) = *(half8*)(h + 8);  // k-half 1 -> lanes 32..63
    *(half8*)&lt[r][q * 16]     = *(half8*)h;
    *(half8*)&lt[r][q * 16 + 8] = *(half8*)(h + 8);
  }
  __syncthreads();
  // transposed side: d = hw, kv = c
  const int d = h0 + r;
  if (d < HW_) {
    f16 g[16];
#pragma unroll
    for (int j = 0; j < 16; ++j) g[j] = lt[q * 16 + j][r];
    const int kt = (c0 >> 4) + q;
    if (d < 768) {
      const int pd = d >> 5, dc = d & 31;
      f16* e0 = mV + ((size_t)pd * 64 + kt) * 512 + dc * 8;
      *(half8*)e0         = *(half8*)g;
      *(half8*)(e0 + 256) = *(half8*)(g + 8);
    } else {
      f16* e0 = tl + kt * 256 + (d & 15) * 8;
      *(half8*)e0         = *(half8*)g;
      *(half8*)(e0 + 128) = *(half8*)(g + 8);
    }
  }
}

// ---------------------------------------------------------------------------
// Main: BQ=64, 1024 threads, 32x32x16 MFMA, NO explicit prefetch (compiler
// schedules; r6 proved this structure doesn't spill).
// ---------------------------------------------------------------------------
__global__ __launch_bounds__(1024, 4)
void chanattn_main(const float* __restrict__ x, const f16* __restrict__ ws,
                   float* __restrict__ out) {
  __shared__ f16 Pl[BQ * C_];   // 128 KiB
  char* Pb = (char*)Pl;

  const int bi   = blockIdx.x;
  const int slot = bi >> 3;
  const int b    = ((slot >> 4) << 3) | (bi & 7);   // same-batch WGs share an XCD
  const int rb   = slot & 15;
  const int q0   = rb * BQ;

  const int tid  = threadIdx.x;
  const int w    = tid >> 6;    // 0..15
  const int lane = tid & 63;
  const int l31  = lane & 31;
  const int lh   = lane >> 5;   // k-half

  const f16* mA = ws + (size_t)b * MA_BATCH;
  const f16* mV = ws + MV_OFF + (size_t)b * MV_BATCH;
  const f16* tl = ws + TL_OFF + (size_t)b * TL_BATCH;

  // ---------------- Phase 1: raw scores S = M[q-rows] . M^T ----------------
  {
    const f16* aB0 = mA + ((size_t)(rb * 2 + 0) * 49) * 512 + lane * 8;
    const f16* aB1 = mA + ((size_t)(rb * 2 + 1) * 49) * 512 + lane * 8;
    const f16* bB0 = mA + ((size_t)(w * 2 + 0) * 49) * 512 + lane * 8;
    const f16* bB1 = mA + ((size_t)(w * 2 + 1) * 49) * 512 + lane * 8;

    f32x16 acc00 = {}, acc01 = {}, acc10 = {}, acc11 = {};
    for (int kt = 0; kt < 49; ++kt) {
      const half8 a0 = *(const half8*)(aB0 + (size_t)kt * 512);
      const half8 a1 = *(const half8*)(aB1 + (size_t)kt * 512);
      const half8 b0 = *(const half8*)(bB0 + (size_t)kt * 512);
      const half8 b1 = *(const half8*)(bB1 + (size_t)kt * 512);
      acc00 = __builtin_amdgcn_mfma_f32_32x32x16_f16(a0, b0, acc00, 0, 0, 0);
      acc01 = __builtin_amdgcn_mfma_f32_32x32x16_f16(a0, b1, acc01, 0, 0, 0);
      acc10 = __builtin_amdgcn_mfma_f32_32x32x16_f16(a1, b0, acc10, 0, 0, 0);
      acc11 = __builtin_amdgcn_mfma_f32_32x32x16_f16(a1, b1, acc11, 0, 0, 0);
    }

    // write raw f16 scores -> P (XOR swizzle (row&7)<<4)
#pragma unroll
    for (int reg = 0; reg < 16; ++reg) {
      const int rloc = (reg & 3) + 8 * (reg >> 2) + 4 * lh;  // C/D row mapping
#define PSTORE(rowv, colv, val) do {                          \
  const int row_ = (rowv); int byte_ = row_ * 2048 + (colv) * 2; \
  byte_ ^= (row_ & 7) << 4;                                   \
  *(f16*)(Pb + byte_) = (f16)(val);                           \
} while (0)
      PSTORE(rloc,      w * 64 + l31,      acc00[reg]);
      PSTORE(rloc,      w * 64 + 32 + l31, acc01[reg]);
      PSTORE(32 + rloc, w * 64 + l31,      acc10[reg]);
      PSTORE(32 + rloc, w * 64 + 32 + l31, acc11[reg]);
    }
  }
  __syncthreads();

  // ---------------- softmax, rows w*4..w*4+3 (lane-consecutive 16B) ----------------
  {
    const float ksc = 0.045084223f;   // log2(e)/32
    for (int rr = 0; rr < 4; ++rr) {
      const int row = w * 4 + rr;
      const int sw  = (row & 7) << 4;
      char* rbase = Pb + row * 2048;
      const int p0 = (lane * 16) ^ sw;
      half8 v0 = *(half8*)(rbase + p0);
      half8 v1 = *(half8*)(rbase + 1024 + p0);
      float f[16];
#pragma unroll
      for (int e = 0; e < 8; ++e) { f[e] = (float)v0[e]; f[e+8] = (float)v1[e]; }
      float mx = f[0];
#pragma unroll
      for (int e = 1; e < 16; ++e) mx = fmaxf(mx, f[e]);
      for (int d = 1; d < 64; d <<= 1) mx = fmaxf(mx, __shfl_xor(mx, d));
      float sum = 0.f;
#pragma unroll
      for (int e = 0; e < 16; ++e) { f[e] = exp2f((f[e] - mx) * ksc); sum += f[e]; }
      for (int d = 1; d < 64; d <<= 1) sum += __shfl_xor(sum, d);
      const float inv = 1.f / sum;
#pragma unroll
      for (int e = 0; e < 8; ++e) { v0[e] = (f16)(f[e]*inv); v1[e] = (f16)(f[e+8]*inv); }
      *(half8*)(rbase + p0) = v0;
      *(half8*)(rbase + 1024 + p0) = v1;
    }
  }
  __syncthreads();

  // ---------------- Phase 2: y = P . V ; out = x + y ----------------
  {
    const bool vok = (l31 < 16);     // valid lanes for the compact tail panel

#define LDPA(kt, pa) do {                                       \
  _Pragma("unroll") for (int ra_ = 0; ra_ < 2; ++ra_) {         \
    const int row_ = ra_ * 32 + l31;                            \
    int byte_ = row_ * 2048 + (kt) * 32 + lh * 16;              \
    byte_ ^= (row_ & 7) << 4;                                   \
    pa[ra_] = *(const half8*)(Pb + byte_); }                    \
} while (0)

#define LDVF(kt, v) do { v = *(const half8*)(vB + (size_t)(kt) * 512 + lane * 8); } while (0)
#define LDVT(kt, v) do {                                        \
  half8 z_ = {};                                                \
  if (vok) z_ = *(const half8*)(tl + (kt) * 256 + lh * 128 + l31 * 8); \
  v = z_;                                                       \
} while (0)

#define PV_PANEL(LDV_) do {                                                         \
  f32x16 p0 = {}, p1 = {};                                                          \
  for (int kt = 0; kt < 64; ++kt) {                                                 \
    half8 pa[2], vv;                                                                \
    LDPA(kt, pa); LDV_(kt, vv);                                                     \
    p0 = __builtin_amdgcn_mfma_f32_32x32x16_f16(pa[0], vv, p0, 0, 0, 0);            \
    p1 = __builtin_amdgcn_mfma_f32_32x32x16_f16(pa[1], vv, p1, 0, 0, 0);            \
  }                                                                                 \
  const int dd = pd * 32 + l31;                                                     \
  if (dd < HW_) {                                                                   \
    _Pragma("unroll") for (int reg_ = 0; reg_ < 16; ++reg_) {                       \
      const int rl_ = (reg_ & 3) + 8 * (reg_ >> 2) + 4 * lh;                        \
      const size_t i0_ = (size_t)(b * C_ + q0 + rl_) * HW_ + dd;                    \
      const size_t i1_ = (size_t)(b * C_ + q0 + 32 + rl_) * HW_ + dd;               \
      out[i0_] = x[i0_] + p0[reg_];                                                 \
      out[i1_] = x[i1_] + p1[reg_];                                                 \
    }                                                                               \
  }                                                                                 \
} while (0)

    for (int si = 0; si < 2; ++si) {
      const int pd = w + 16 * si;
      if (pd >= 25) break;                     // wave-uniform
      if (pd < 24) {
        const f16* vB = mV + (size_t)pd * 64 * 512;
        PV_PANEL(LDVF);
      } else {
        PV_PANEL(LDVT);
      }
    }
  }
}

// ---------------------------------------------------------------------------
// Fallback (round-1 kernel): only if ws too small.
// ---------------------------------------------------------------------------
__device__ __forceinline__ half8 pack8(const float4& a, const float4& b) {
  half8 r;
  r[0]=(f16)a.x; r[1]=(f16)a.y; r[2]=(f16)a.z; r[3]=(f16)a.w;
  r[4]=(f16)b.x; r[5]=(f16)b.y; r[6]=(f16)b.z; r[7]=(f16)b.w;
  return r;
}

__global__ __launch_bounds__(512, 2)
void chanattn_fallback(const float* __restrict__ x, float* __restrict__ out) {
  __shared__ f16 Pl[64 * C_];
  const int bi   = blockIdx.x;
  const int slot = bi >> 3;
  const int b    = ((slot >> 4) << 3) | (bi & 7);
  const int rb   = slot & 15;
  const int q0   = rb * 64;
  const int tid  = threadIdx.x;
  const int w    = tid >> 6;
  const int lane = tid & 63;
  const int l15  = lane & 15;
  const int l4   = lane >> 4;
  const float* mb = x + (size_t)b * (C_ * HW_);
  char* Pb = (char*)Pl;
  {
    const int cw = w * 128;
    for (int tile = 0; tile < 2; ++tile) {
      const int c0 = cw + tile * 64;
      f32x4 acc[4][4] = {};
      for (int kc = 0; kc < 25; ++kc) {
        const int k0 = kc * 32 + l4 * 8;
        const bool ok = (k0 < HW_);
        half8 afr[4], bfr[4];
#pragma unroll
        for (int rf = 0; rf < 4; ++rf) {
          if (ok) { const float4* p = (const float4*)(mb + (q0 + rf*16 + l15) * HW_ + k0); afr[rf] = pack8(p[0], p[1]); }
          else {
#pragma unroll
            for (int e = 0; e < 8; ++e) afr[rf][e] = (f16)0.f; }
        }
#pragma unroll
        for (int cf = 0; cf < 4; ++cf) {
          if (ok) { const float4* p = (const float4*)(mb + (c0 + cf*16 + l15) * HW_ + k0); bfr[cf] = pack8(p[0], p[1]); }
          else {
#pragma unroll
            for (int e = 0; e < 8; ++e) bfr[cf][e] = (f16)0.f; }
        }
#pragma unroll
        for (int rf = 0; rf < 4; ++rf)
#pragma unroll
          for (int cf = 0; cf < 4; ++cf)
            acc[rf][cf] = __builtin_amdgcn_mfma_f32_16x16x32_f16(afr[rf], bfr[cf], acc[rf][cf], 0, 0, 0);
      }
#pragma unroll
      for (int rf = 0; rf < 4; ++rf)
#pragma unroll
        for (int cf = 0; cf < 4; ++cf)
#pragma unroll
          for (int r = 0; r < 4; ++r) {
            const int row = rf*16 + l4*4 + r;
            const int col = c0 + cf*16 + l15;
            int byte = row*2048 + col*2;
            byte ^= (row & 7) << 4;
            *(f16*)(Pb + byte) = (f16)acc[rf][cf][r];
          }
    }
  }
  __syncthreads();
  {
    const float ksc = 0.045084223f;
    for (int rr = 0; rr < 8; ++rr) {
      const int row = w*8 + rr;
      const int sw  = (row & 7) << 4;
      char* rbase = Pb + row*2048;
      const int p0 = (lane * 16) ^ sw;
      half8 v0 = *(half8*)(rbase + p0);
      half8 v1 = *(half8*)(rbase + 1024 + p0);
      float f[16];
#pragma unroll
      for (int e = 0; e < 8; ++e) { f[e] = (float)v0[e]; f[e+8] = (float)v1[e]; }
      float mx = f[0];
#pragma unroll
      for (int e = 1; e < 16; ++e) mx = fmaxf(mx, f[e]);
      for (int d = 1; d < 64; d <<= 1) mx = fmaxf(mx, __shfl_xor(mx, d));
      float sum = 0.f;
#pragma unroll
      for (int e = 0; e < 16; ++e) { f[e] = exp2f((f[e] - mx) * ksc); sum += f[e]; }
      for (int d = 1; d < 64; d <<= 1) sum += __shfl_xor(sum, d);
      const float inv = 1.f / sum;
#pragma unroll
      for (int e = 0; e < 8; ++e) { v0[e] = (f16)(f[e]*inv); v1[e] = (f16)(f[e+8]*inv); }
      *(half8*)(rbase + p0) = v0;
      *(half8*)(rbase + 1024 + p0) = v1;
    }
  }
  __syncthreads();
  {
    f32x4 acc[7][4] = {};
    for (int t = 0; t < 16; ++t) {
      half8 afr[4][2];
#pragma unroll
      for (int rf = 0; rf < 4; ++rf)
#pragma unroll
        for (int kf = 0; kf < 2; ++kf) {
          const int row = rf*16 + l15;
          int byte = row*2048 + t*128 + kf*64 + l4*16;
          byte ^= (row & 7) << 4;
          afr[rf][kf] = *(half8*)(Pb + byte);
        }
#pragma unroll
      for (int si = 0; si < 7; ++si) {
        const int s = w + 8*si;
        if (s < 49) {
          const int d = s*16 + l15;
#pragma unroll
          for (int kf = 0; kf < 2; ++kf) {
            const int kv = t*64 + kf*32 + l4*8;
            half8 bfr;
#pragma unroll
            for (int e = 0; e < 8; ++e) bfr[e] = (f16)mb[(kv + e) * HW_ + d];
#pragma unroll
            for (int rf = 0; rf < 4; ++rf)
              acc[si][rf] = __builtin_amdgcn_mfma_f32_16x16x32_f16(afr[rf][kf], bfr, acc[si][rf], 0, 0, 0);
          }
        }
      }
    }
#pragma unroll
    for (int si = 0; si < 7; ++si) {
      const int s = w + 8*si;
      if (s < 49) {
        const int d = s*16 + l15;
#pragma unroll
        for (int rf = 0; rf < 4; ++rf)
#pragma unroll
          for (int r = 0; r < 4; ++r) {
            const size_t idx = (size_t)(b*C_ + q0 + rf*16 + l4*4 + r) * HW_ + d;
            out[idx] = x[idx] + acc[si][rf][r];
          }
      }
    }
  }
}

extern "C" void kernel_launch(void* const* d_in, const int* in_sizes, int n_in,
                              void* d_out, int out_size, void* d_ws, size_t ws_size,
                              hipStream_t stream) {
  const float* x = (const float*)d_in[0];
  float* out = (float*)d_out;
  const size_t need = (TL_OFF + 32ull * TL_BATCH) * 2;   // 102,760,448 B
  if (ws_size >= need) {
    f16* ws = (f16*)d_ws;
    prep_kernel<<<dim3(32 * 16 * 13), dim3(256), 0, stream>>>(x, ws);
    chanattn_main<<<dim3(512), dim3(1024), 0, stream>>>(x, ws, out);
  } else {
    chanattn_fallback<<<dim3(512), dim3(512), 0, stream>>>(x, out);
  }
}